// Round 1
// baseline (12995.703 us; speedup 1.0000x reference)
//
#include <hip/hip_runtime.h>
#include <math.h>

#define IMH 192
#define IMW 192
#define HWF (IMH*IMW)   // 36864

__device__ __forceinline__ float sigmoidf(float x){ return 1.f/(1.f+expf(-x)); }

__device__ __forceinline__ float bilin(const float* __restrict__ img, float ys, float xs, int H, int W){
  float y0f = floorf(ys), x0f = floorf(xs);
  float wy = ys - y0f, wx = xs - x0f;
  int y0 = (int)y0f, x0 = (int)x0f;
  float acc = 0.f;
  #pragma unroll
  for (int dy=0; dy<2; ++dy){
    int yi = y0+dy;
    float wyv = dy ? wy : 1.f-wy;
    if (yi < 0 || yi >= H) continue;
    #pragma unroll
    for (int dx=0; dx<2; ++dx){
      int xi = x0+dx;
      float wxv = dx ? wx : 1.f-wx;
      if (xi < 0 || xi >= W) continue;
      acc += img[yi*W+xi]*(wyv*wxv);
    }
  }
  return acc;
}

// Generic 3x3 conv, pad=1, stride s, NCHW, weight OIHW. act: 0=none 1=relu 2=lrelu(0.1)
__global__ __launch_bounds__(256) void conv3x3_k(
    const float* __restrict__ in, const float* __restrict__ w,
    const float* __restrict__ bias, float* __restrict__ out,
    int Cin, int Hin, int Win, int Hout, int Wout, int stride, int act)
{
  int o = blockIdx.y;
  int Cout = gridDim.y;
  int n = blockIdx.z;
  int idx = blockIdx.x*blockDim.x + threadIdx.x;
  if (idx >= Hout*Wout) return;
  int oy = idx / Wout, ox = idx % Wout;
  int y0 = oy*stride - 1, x0 = ox*stride - 1;
  const float* inb = in + (size_t)n*Cin*Hin*Win;
  const float* wp = w + (size_t)o*Cin*9;
  // precompute validity
  bool ry[3], rx[3];
  #pragma unroll
  for (int d=0; d<3; ++d){ ry[d] = (y0+d >= 0) && (y0+d < Hin); rx[d] = (x0+d >= 0) && (x0+d < Win); }
  float acc = bias[o];
  for (int c = 0; c < Cin; ++c){
    const float* ip = inb + (size_t)c*Hin*Win;
    #pragma unroll
    for (int dy=0; dy<3; ++dy){
      if (!ry[dy]) continue;
      const float* rp = ip + (y0+dy)*Win + x0;
      #pragma unroll
      for (int dx=0; dx<3; ++dx){
        if (!rx[dx]) continue;
        acc += rp[dx]*wp[c*9 + dy*3 + dx];
      }
    }
  }
  if (act == 1) acc = fmaxf(acc, 0.f);
  else if (act == 2) acc = acc > 0.f ? acc : 0.1f*acc;
  out[((size_t)n*Cout + o)*(size_t)(Hout*Wout) + idx] = acc;
}

// gating + flow-warp: s[t*64+c] = a*sig(a*r) + p*sig(p*r)
__global__ __launch_bounds__(256) void gate_k(
    const float* __restrict__ feat, const float* __restrict__ pred,
    const float* __restrict__ mv, float* __restrict__ sOut)
{
  int idx = blockIdx.x*blockDim.x + threadIdx.x;
  if (idx >= HWF) return;
  int c = blockIdx.y, t = blockIdx.z;
  float r = feat[(size_t)(3*64 + c)*HWF + idx];
  float p = pred[(size_t)(t*64 + c)*HWF + idx];
  float a;
  if (t == 0){
    a = feat[(size_t)c*HWF + idx];
  } else {
    int h = idx / IMW, x = idx % IMW;
    float fx = mv[((size_t)(t-1)*HWF + idx)*2 + 0];
    float fy = mv[((size_t)(t-1)*HWF + idx)*2 + 1];
    a = bilin(feat + (size_t)((t-1)*64 + c)*HWF, (float)h + fy, (float)x + fx, IMH, IMW);
  }
  sOut[(size_t)(t*64 + c)*HWF + idx] = a*sigmoidf(a*r) + p*sigmoidf(p*r);
}

// out0 = 0.1*lrelu(conv(s)+b) + lrelu(conv(f)+b), Cin=448, shared weights
__global__ __launch_bounds__(256) void fuse_k(
    const float* __restrict__ s, const float* __restrict__ f,
    const float* __restrict__ w, const float* __restrict__ bias,
    float* __restrict__ out)
{
  int o = blockIdx.y;
  int idx = blockIdx.x*blockDim.x + threadIdx.x;
  if (idx >= HWF) return;
  int oy = idx / IMW, ox = idx % IMW;
  int y0 = oy - 1, x0 = ox - 1;
  bool ry[3], rx[3];
  #pragma unroll
  for (int d=0; d<3; ++d){ ry[d] = (y0+d >= 0) && (y0+d < IMH); rx[d] = (x0+d >= 0) && (x0+d < IMW); }
  const float* wp = w + (size_t)o*448*9;
  float a1 = 0.f, a2 = 0.f;
  for (int c = 0; c < 448; ++c){
    const float* sp = s + (size_t)c*HWF;
    const float* fp = f + (size_t)c*HWF;
    #pragma unroll
    for (int dy=0; dy<3; ++dy){
      if (!ry[dy]) continue;
      int rb = (y0+dy)*IMW + x0;
      #pragma unroll
      for (int dx=0; dx<3; ++dx){
        if (!rx[dx]) continue;
        float wv = wp[c*9 + dy*3 + dx];
        a1 += sp[rb+dx]*wv;
        a2 += fp[rb+dx]*wv;
      }
    }
  }
  a1 += bias[o]; a2 += bias[o];
  a1 = a1 > 0.f ? a1 : 0.1f*a1;
  a2 = a2 > 0.f ? a2 : 0.1f*a2;
  out[(size_t)o*HWF + idx] = 0.1f*a1 + a2;
}

// ConvTranspose2d k=4 s=2 p=1, C=64->64, weight (I,O,4,4), relu
__global__ __launch_bounds__(256) void convT_k(
    const float* __restrict__ in, const float* __restrict__ w,
    const float* __restrict__ bias, float* __restrict__ out,
    int Hin, int Win)
{
  int Hout = 2*Hin, Wout = 2*Win;
  int o = blockIdx.y;
  int idx = blockIdx.x*blockDim.x + threadIdx.x;
  if (idx >= Hout*Wout) return;
  int p = idx / Wout, q = idx % Wout;
  int ay[2], ka[2], na = 0;
  #pragma unroll
  for (int a=0; a<4; ++a){
    int u = p + a - 2;
    if (u >= 0 && (u & 1) == 0 && (u >> 1) < Hin){ ay[na] = u >> 1; ka[na] = 3 - a; ++na; }
  }
  int bx[2], kb[2], nb = 0;
  #pragma unroll
  for (int b=0; b<4; ++b){
    int u = q + b - 2;
    if (u >= 0 && (u & 1) == 0 && (u >> 1) < Win){ bx[nb] = u >> 1; kb[nb] = 3 - b; ++nb; }
  }
  float acc = bias[o];
  for (int i = 0; i < 64; ++i){
    const float* ip = in + (size_t)i*Hin*Win;
    const float* wpi = w + (size_t)(i*64 + o)*16;
    for (int ii=0; ii<na; ++ii)
      for (int jj=0; jj<nb; ++jj)
        acc += ip[ay[ii]*Win + bx[jj]] * wpi[ka[ii]*4 + kb[jj]];
  }
  out[(size_t)o*(Hout*Wout) + idx] = fmaxf(acc, 0.f);
}

// modulated deformable conv (G=7 groups of 1 ch), K=9, + relu
__global__ __launch_bounds__(256) void deform_k(
    const float* __restrict__ lqs, const float* __restrict__ om,
    const float* __restrict__ dcw, const float* __restrict__ dcb,
    float* __restrict__ out)
{
  int idx = blockIdx.x*blockDim.x + threadIdx.x;
  if (idx >= HWF) return;
  int h = idx / IMW, x = idx % IMW;
  float v[63];
  #pragma unroll
  for (int g = 0; g < 7; ++g){
    const float* img = lqs + (size_t)g*HWF;
    #pragma unroll
    for (int k = 0; k < 9; ++k){
      int j = g*9 + k;
      float offy = om[(size_t)(j*2 + 0)*HWF + idx];
      float offx = om[(size_t)(j*2 + 1)*HWF + idx];
      float m = sigmoidf(om[(size_t)(126 + j)*HWF + idx]);
      float ys = (float)(h + (k/3) - 1) + offy;
      float xs = (float)(x + (k%3) - 1) + offx;
      v[j] = bilin(img, ys, xs, IMH, IMW) * m;
    }
  }
  for (int o = 0; o < 64; ++o){
    float acc = dcb[o];
    #pragma unroll
    for (int j = 0; j < 63; ++j) acc += v[j]*dcw[o*63 + j];
    out[(size_t)o*HWF + idx] = fmaxf(acc, 0.f);
  }
}

extern "C" void kernel_launch(void* const* d_in, const int* in_sizes, int n_in,
                              void* d_out, int out_size, void* d_ws, size_t ws_size,
                              hipStream_t stream)
{
  const float* lqs   = (const float*)d_in[0];
  const float* preds = (const float*)d_in[1];
  const float* mv    = (const float*)d_in[2];
  const float* bw1   = (const float*)d_in[3];
  const float* bb1   = (const float*)d_in[4];
  const float* bw2   = (const float*)d_in[5];
  const float* bb2   = (const float*)d_in[6];
  const float* dn1w  = (const float*)d_in[7];
  const float* dn1b  = (const float*)d_in[8];
  const float* dn2w  = (const float*)d_in[9];
  const float* dn2b  = (const float*)d_in[10];
  const float* up1cw = (const float*)d_in[11];
  const float* up1cb = (const float*)d_in[12];
  const float* up1tw = (const float*)d_in[13];
  const float* up1tb = (const float*)d_in[14];
  const float* up2cw = (const float*)d_in[15];
  const float* up2cb = (const float*)d_in[16];
  const float* up2tw = (const float*)d_in[17];
  const float* up2tb = (const float*)d_in[18];
  const float* trcw  = (const float*)d_in[19];
  const float* trcb  = (const float*)d_in[20];
  const float* trtw  = (const float*)d_in[21];
  const float* trtb  = (const float*)d_in[22];
  const float* ffw   = (const float*)d_in[23];
  const float* ffb   = (const float*)d_in[24];
  const float* omw   = (const float*)d_in[25];
  const float* omb   = (const float*)d_in[26];
  const float* dcw   = (const float*)d_in[27];
  const float* dcb   = (const float*)d_in[28];
  float* outp = (float*)d_out;

  float* ws = (float*)d_ws;
  const size_t NBIG = (size_t)7*64*HWF;        // 16,515,072
  float* feat = ws;                             // [0, NBIG)
  float* pred = ws + NBIG;                      // [NBIG, 2*NBIG)
  float* tmp  = ws + 2*NBIG;                    // [2*NBIG, 3*NBIG)  bb-mid / s / off_msk
  // overlay small tensors onto pred region (dead after gate_k)
  float* out0  = pred;                          // 64*36864
  float* cat1  = pred + 2359296;                // 128*9216: [u2t | out1]
  float* cat2  = pred + 3538944;                // 128*2304: [t1 | out2]
  float* t0    = pred + 3833856;                // 64*576
  float* u2    = pred + 3870720;                // 64*2304
  float* u1    = pred + 4018176;                // 64*9216
  float* featf = pred + 4608000;                // 64*36864
  float* out1  = cat1 + 64*9216;
  float* out2  = cat2 + 64*2304;
  float* t1    = cat2;
  float* u2t   = cat1;

  dim3 blk(256);
  // backbone: feat = bb(lqs), pred = bb(preds)
  conv3x3_k<<<dim3(144,64,7), blk, 0, stream>>>(lqs,  bw1, bb1, tmp,  1,  IMH,IMW,IMH,IMW, 1, 0);
  conv3x3_k<<<dim3(144,64,7), blk, 0, stream>>>(tmp,  bw2, bb2, feat, 64, IMH,IMW,IMH,IMW, 1, 0);
  conv3x3_k<<<dim3(144,64,7), blk, 0, stream>>>(preds,bw1, bb1, tmp,  1,  IMH,IMW,IMH,IMW, 1, 0);
  conv3x3_k<<<dim3(144,64,7), blk, 0, stream>>>(tmp,  bw2, bb2, pred, 64, IMH,IMW,IMH,IMW, 1, 0);
  // gating (+flow warp) -> s in tmp  (NOTE: must run before out0 overlay writes pred region)
  gate_k<<<dim3(144,64,7), blk, 0, stream>>>(feat, pred, mv, tmp);
  // out0 = 0.1*fuse(s) + fuse(feat-as-448ch)
  fuse_k<<<dim3(144,64), blk, 0, stream>>>(tmp, feat, ffw, ffb, out0);
  // U-Net
  conv3x3_k<<<dim3(36,64,1), blk, 0, stream>>>(out0, dn1w, dn1b, out1, 64, 192,192, 96,96, 2, 1);
  conv3x3_k<<<dim3(9,64,1),  blk, 0, stream>>>(out1, dn2w, dn2b, out2, 64,  96, 96, 48,48, 2, 1);
  conv3x3_k<<<dim3(3,64,1),  blk, 0, stream>>>(out2, trcw, trcb, t0,   64,  48, 48, 24,24, 2, 1);
  convT_k  <<<dim3(9,64),    blk, 0, stream>>>(t0, trtw, trtb, t1, 24,24);
  conv3x3_k<<<dim3(9,64,1),  blk, 0, stream>>>(cat2, up2cw, up2cb, u2, 128, 48,48, 48,48, 1, 1);
  convT_k  <<<dim3(36,64),   blk, 0, stream>>>(u2, up2tw, up2tb, u2t, 48,48);
  conv3x3_k<<<dim3(36,64,1), blk, 0, stream>>>(cat1, up1cw, up1cb, u1, 128, 96,96, 96,96, 1, 1);
  convT_k  <<<dim3(144,64),  blk, 0, stream>>>(u1, up1tw, up1tb, featf, 96,96);
  // offsets/masks (189 ch) -> tmp (s is dead)
  conv3x3_k<<<dim3(144,189,1), blk, 0, stream>>>(featf, omw, omb, tmp, 64, 192,192,192,192, 1, 0);
  // deformable conv + relu -> out
  deform_k<<<dim3(144), blk, 0, stream>>>(lqs, tmp, dcw, dcb, outp);
}

// Round 2
// 3996.855 us; speedup vs baseline: 3.2515x; 3.2515x over previous
//
#include <hip/hip_runtime.h>
#include <math.h>

#define IMH 192
#define IMW 192
#define HWF 36864

__device__ __forceinline__ float sigmoidf(float x){ return 1.f/(1.f+expf(-x)); }
__device__ __forceinline__ float lrelu(float x){ return x > 0.f ? x : 0.1f*x; }

__device__ __forceinline__ float bilin(const float* __restrict__ img, float ys, float xs, int H, int W){
  float y0f = floorf(ys), x0f = floorf(xs);
  float wy = ys - y0f, wx = xs - x0f;
  int y0 = (int)y0f, x0 = (int)x0f;
  float acc = 0.f;
  #pragma unroll
  for (int dy=0; dy<2; ++dy){
    int yi = y0+dy;
    float wyv = dy ? wy : 1.f-wy;
    if (yi < 0 || yi >= H) continue;
    #pragma unroll
    for (int dx=0; dx<2; ++dx){
      int xi = x0+dx;
      float wxv = dx ? wx : 1.f-wx;
      if (xi < 0 || xi >= W) continue;
      acc += img[yi*W+xi]*(wyv*wxv);
    }
  }
  return acc;
}

// ---------------- tiled 3x3 stride-1 conv ----------------
// grid: (ceil(Cout/4), tiles, n). block 256. tile = 32x32 out pixels,
// thread = 2x2 pixels x 4 outs. LDS stages CC channels (pitch 35).
template<int CC, int ACT>
__global__ __launch_bounds__(256) void conv3x3_tile(
    const float* __restrict__ in, const float* __restrict__ w,
    const float* __restrict__ bias, float* __restrict__ out,
    int Cin, int Cout, int H, int tilesX)
{
  __shared__ float sIn[CC][34*35];
  __shared__ float sW[CC][4][9];
  const int W = H;
  const int og = blockIdx.x, tile = blockIdx.y, n = blockIdx.z;
  const int ty0 = (tile/tilesX)*32, tx0 = (tile%tilesX)*32;
  const int o0 = og*4;
  const int tid = threadIdx.x;
  const float* inb = in + (size_t)n*Cin*H*W;
  const int py = 2*(tid>>4), px = 2*(tid&15);
  float acc[4][2][2] = {};
  for (int cb = 0; cb < Cin; cb += CC){
    for (int i = tid; i < CC*36; i += 256){
      int c = i/36, r = i%36, ol = r/9, k = r%9;
      int o = o0 + ol;
      float v = 0.f;
      if (o < Cout && cb + c < Cin) v = w[((size_t)o*Cin + cb + c)*9 + k];
      sW[c][ol][k] = v;
    }
    for (int i = tid; i < CC*1156; i += 256){
      int c = i/1156, rem = i%1156, r = rem/34, col = rem%34;
      int gy = ty0 - 1 + r, gx = tx0 - 1 + col;
      float v = 0.f;
      if (cb + c < Cin && gy >= 0 && gy < H && gx >= 0 && gx < W)
        v = inb[(size_t)(cb + c)*H*W + gy*W + gx];
      sIn[c][r*35 + col] = v;
    }
    __syncthreads();
    #pragma unroll
    for (int c = 0; c < CC; ++c){
      float t[4][4];
      #pragma unroll
      for (int dy = 0; dy < 4; ++dy)
        #pragma unroll
        for (int dx = 0; dx < 4; ++dx) t[dy][dx] = sIn[c][(py+dy)*35 + px+dx];
      #pragma unroll
      for (int ol = 0; ol < 4; ++ol){
        float wv[9];
        #pragma unroll
        for (int k = 0; k < 9; ++k) wv[k] = sW[c][ol][k];
        #pragma unroll
        for (int iy = 0; iy < 2; ++iy)
          #pragma unroll
          for (int ix = 0; ix < 2; ++ix){
            float a = acc[ol][iy][ix];
            #pragma unroll
            for (int dy = 0; dy < 3; ++dy)
              #pragma unroll
              for (int dx = 0; dx < 3; ++dx) a += t[iy+dy][ix+dx]*wv[dy*3+dx];
            acc[ol][iy][ix] = a;
          }
      }
    }
    __syncthreads();
  }
  #pragma unroll
  for (int ol = 0; ol < 4; ++ol){
    int o = o0 + ol;
    if (o >= Cout) continue;
    float b = bias[o];
    #pragma unroll
    for (int iy = 0; iy < 2; ++iy){
      int gy = ty0 + py + iy;
      if (gy >= H) continue;
      #pragma unroll
      for (int ix = 0; ix < 2; ++ix){
        int gx = tx0 + px + ix;
        if (gx >= W) continue;
        float v = acc[ol][iy][ix] + b;
        if (ACT == 1) v = fmaxf(v, 0.f); else if (ACT == 2) v = lrelu(v);
        out[((size_t)n*Cout + o)*(size_t)(H*W) + (size_t)gy*W + gx] = v;
      }
    }
  }
}

// ---------------- fused dual conv (out0 = 0.1*lrelu(conv(s)) + lrelu(conv(f))) ----------------
__global__ __launch_bounds__(256) void fuse_tile(
    const float* __restrict__ s, const float* __restrict__ f,
    const float* __restrict__ w, const float* __restrict__ bias,
    float* __restrict__ out)
{
  const int CC = 2;
  __shared__ float sS[CC][34*35];
  __shared__ float sF[CC][34*35];
  __shared__ float sW[CC][4][9];
  const int og = blockIdx.x, tile = blockIdx.y;
  const int ty0 = (tile/6)*32, tx0 = (tile%6)*32;
  const int o0 = og*4;
  const int tid = threadIdx.x;
  const int py = 2*(tid>>4), px = 2*(tid&15);
  float a1[4][2][2] = {}, a2[4][2][2] = {};
  for (int cb = 0; cb < 448; cb += CC){
    for (int i = tid; i < CC*36; i += 256){
      int c = i/36, r = i%36, ol = r/9, k = r%9;
      sW[c][ol][k] = w[((size_t)(o0+ol)*448 + cb + c)*9 + k];
    }
    for (int i = tid; i < CC*1156; i += 256){
      int c = i/1156, rem = i%1156, r = rem/34, col = rem%34;
      int gy = ty0 - 1 + r, gx = tx0 - 1 + col;
      float vs = 0.f, vf = 0.f;
      if (gy >= 0 && gy < IMH && gx >= 0 && gx < IMW){
        size_t off = (size_t)(cb + c)*HWF + gy*IMW + gx;
        vs = s[off]; vf = f[off];
      }
      sS[c][r*35 + col] = vs;
      sF[c][r*35 + col] = vf;
    }
    __syncthreads();
    #pragma unroll
    for (int c = 0; c < CC; ++c){
      float ts[4][4], tf[4][4];
      #pragma unroll
      for (int dy = 0; dy < 4; ++dy)
        #pragma unroll
        for (int dx = 0; dx < 4; ++dx){
          ts[dy][dx] = sS[c][(py+dy)*35 + px+dx];
          tf[dy][dx] = sF[c][(py+dy)*35 + px+dx];
        }
      #pragma unroll
      for (int ol = 0; ol < 4; ++ol){
        float wv[9];
        #pragma unroll
        for (int k = 0; k < 9; ++k) wv[k] = sW[c][ol][k];
        #pragma unroll
        for (int iy = 0; iy < 2; ++iy)
          #pragma unroll
          for (int ix = 0; ix < 2; ++ix){
            float u1 = a1[ol][iy][ix], u2 = a2[ol][iy][ix];
            #pragma unroll
            for (int dy = 0; dy < 3; ++dy)
              #pragma unroll
              for (int dx = 0; dx < 3; ++dx){
                float wvv = wv[dy*3+dx];
                u1 += ts[iy+dy][ix+dx]*wvv;
                u2 += tf[iy+dy][ix+dx]*wvv;
              }
            a1[ol][iy][ix] = u1; a2[ol][iy][ix] = u2;
          }
      }
    }
    __syncthreads();
  }
  #pragma unroll
  for (int ol = 0; ol < 4; ++ol){
    int o = o0 + ol;
    float b = bias[o];
    #pragma unroll
    for (int iy = 0; iy < 2; ++iy)
      #pragma unroll
      for (int ix = 0; ix < 2; ++ix){
        int gy = ty0 + py + iy, gx = tx0 + px + ix;
        float v = 0.1f*lrelu(a1[ol][iy][ix] + b) + lrelu(a2[ol][iy][ix] + b);
        out[(size_t)o*HWF + (size_t)gy*IMW + gx] = v;
      }
  }
}

// ---------------- tiled 3x3 stride-2 conv (relu) ----------------
// grid: (Cout/4, tiles). tile = 16x16 out pixels, thread = 1 pixel x 4 outs.
__global__ __launch_bounds__(256) void conv3x3s2_tile(
    const float* __restrict__ in, const float* __restrict__ w,
    const float* __restrict__ bias, float* __restrict__ out,
    int Cin, int Cout, int Hin, int Hout, int tilesX)
{
  const int CC = 4;
  __shared__ float sIn[CC][33*35];
  __shared__ float sW[CC][4][9];
  const int Win = Hin, Wout = Hout;
  const int og = blockIdx.x, tile = blockIdx.y;
  const int ty0 = (tile/tilesX)*16, tx0 = (tile%tilesX)*16;
  const int o0 = og*4;
  const int tid = threadIdx.x;
  const int py = tid>>4, px = tid&15;
  float acc[4] = {};
  for (int cb = 0; cb < Cin; cb += CC){
    for (int i = tid; i < CC*36; i += 256){
      int c = i/36, r = i%36, ol = r/9, k = r%9;
      int o = o0 + ol;
      float v = 0.f;
      if (o < Cout) v = w[((size_t)o*Cin + cb + c)*9 + k];
      sW[c][ol][k] = v;
    }
    for (int i = tid; i < CC*1089; i += 256){
      int c = i/1089, rem = i%1089, r = rem/33, col = rem%33;
      int gy = 2*ty0 - 1 + r, gx = 2*tx0 - 1 + col;
      float v = 0.f;
      if (gy >= 0 && gy < Hin && gx >= 0 && gx < Win)
        v = in[(size_t)(cb + c)*Hin*Win + gy*Win + gx];
      sIn[c][r*35 + col] = v;
    }
    __syncthreads();
    #pragma unroll
    for (int c = 0; c < CC; ++c){
      float t[3][3];
      #pragma unroll
      for (int dy = 0; dy < 3; ++dy)
        #pragma unroll
        for (int dx = 0; dx < 3; ++dx) t[dy][dx] = sIn[c][(2*py+dy)*35 + 2*px+dx];
      #pragma unroll
      for (int ol = 0; ol < 4; ++ol){
        float a = acc[ol];
        #pragma unroll
        for (int k = 0; k < 9; ++k) a += t[k/3][k%3]*sW[c][ol][k];
        acc[ol] = a;
      }
    }
    __syncthreads();
  }
  int gy = ty0 + py, gx = tx0 + px;
  if (gy < Hout && gx < Wout){
    #pragma unroll
    for (int ol = 0; ol < 4; ++ol){
      int o = o0 + ol;
      if (o >= Cout) continue;
      float v = fmaxf(acc[ol] + bias[o], 0.f);
      out[(size_t)o*Hout*Wout + (size_t)gy*Wout + gx] = v;
    }
  }
}

// ---------------- convT 4x4 s2 p1 (+relu): prepack weights by output parity ----------------
__global__ __launch_bounds__(256) void repack_convT_w(const float* __restrict__ w, float* __restrict__ wp){
  int id = blockIdx.x*256 + threadIdx.x;   // 16384 total
  int par = id >> 12, o = (id >> 6) & 63, i = id & 63;
  int ry = par >> 1, rx = par & 1;
  #pragma unroll
  for (int jy = 0; jy < 2; ++jy)
    #pragma unroll
    for (int jx = 0; jx < 2; ++jx){
      int ka = 3 - ry - 2*jy, kb = 3 - rx - 2*jx;
      wp[((size_t)((par*64 + o)*64 + i))*4 + jy*2 + jx] = w[((size_t)(i*64 + o))*16 + ka*4 + kb];
    }
}

// grid: (4 o-groups of 16, tiles). tile = 16x16 out pixels, thread = 1 pixel x 16 outs.
__global__ __launch_bounds__(256) void convT_tile(
    const float* __restrict__ in, const float* __restrict__ wp,
    const float* __restrict__ bias, float* __restrict__ out,
    int Hin, int tilesX)
{
  const int CC = 4;
  __shared__ float sIn[CC][10*11];
  __shared__ float sW[16][CC][4][4];   // [ol][ci][par][j]
  const int Win = Hin, Hout = 2*Hin, Wout = 2*Hin;
  const int o0 = blockIdx.x*16;
  const int tile = blockIdx.y;
  const int ty0 = (tile/tilesX)*16, tx0 = (tile%tilesX)*16;
  const int tid = threadIdx.x;
  const int py = tid>>4, px = tid&15;
  const int ry = py&1, rx = px&1, par = ry*2 + rx;
  const int lr = py>>1, lc = px>>1;
  const int r0 = ty0>>1, c0 = tx0>>1;
  float acc[16] = {};
  for (int ib = 0; ib < 64; ib += CC){
    for (int i = tid; i < CC*100; i += 256){
      int c = i/100, rem = i%100, r = rem/10, col = rem%10;
      int gy = r0 - 1 + r, gx = c0 - 1 + col;
      float v = 0.f;
      if (gy >= 0 && gy < Hin && gx >= 0 && gx < Win)
        v = in[(size_t)(ib + c)*Hin*Win + gy*Win + gx];
      sIn[c][r*11 + col] = v;
    }
    for (int i = tid; i < 1024; i += 256){
      int ol = i >> 6, rem = i & 63, ci = rem >> 4, p2 = (rem >> 2) & 3, j = rem & 3;
      sW[ol][ci][p2][j] = wp[((size_t)((p2*64 + o0 + ol)*64) + ib + ci)*4 + j];
    }
    __syncthreads();
    #pragma unroll
    for (int ci = 0; ci < CC; ++ci){
      int rb = lr + ry, cb = lc + rx;
      float t00 = sIn[ci][rb*11 + cb],     t01 = sIn[ci][rb*11 + cb + 1];
      float t10 = sIn[ci][(rb+1)*11 + cb], t11 = sIn[ci][(rb+1)*11 + cb + 1];
      #pragma unroll
      for (int ol = 0; ol < 16; ++ol){
        const float* wv = &sW[ol][ci][par][0];
        acc[ol] += t00*wv[0] + t01*wv[1] + t10*wv[2] + t11*wv[3];
      }
    }
    __syncthreads();
  }
  int gy = ty0 + py, gx = tx0 + px;
  #pragma unroll
  for (int ol = 0; ol < 16; ++ol){
    int o = o0 + ol;
    out[(size_t)o*Hout*Wout + (size_t)gy*Wout + gx] = fmaxf(acc[ol] + bias[o], 0.f);
  }
}

// ---------------- gating + flow-warp ----------------
__global__ __launch_bounds__(256) void gate_k(
    const float* __restrict__ feat, const float* __restrict__ pred,
    const float* __restrict__ mv, float* __restrict__ sOut)
{
  int idx = blockIdx.x*blockDim.x + threadIdx.x;
  if (idx >= HWF) return;
  int c = blockIdx.y, t = blockIdx.z;
  float r = feat[(size_t)(3*64 + c)*HWF + idx];
  float p = pred[(size_t)(t*64 + c)*HWF + idx];
  float a;
  if (t == 0){
    a = feat[(size_t)c*HWF + idx];
  } else {
    int h = idx / IMW, x = idx % IMW;
    float fx = mv[((size_t)(t-1)*HWF + idx)*2 + 0];
    float fy = mv[((size_t)(t-1)*HWF + idx)*2 + 1];
    a = bilin(feat + (size_t)((t-1)*64 + c)*HWF, (float)h + fy, (float)x + fx, IMH, IMW);
  }
  sOut[(size_t)(t*64 + c)*HWF + idx] = a*sigmoidf(a*r) + p*sigmoidf(p*r);
}

// ---------------- deformable conv: sampling then dense ----------------
__global__ __launch_bounds__(256) void deform_sample_k(
    const float* __restrict__ lqs, const float* __restrict__ om,
    float* __restrict__ vbuf)
{
  int idx = blockIdx.x*256 + threadIdx.x;
  int g = blockIdx.y;
  int h = idx / IMW, x = idx % IMW;
  const float* img = lqs + (size_t)g*HWF;
  #pragma unroll
  for (int k = 0; k < 9; ++k){
    int j = g*9 + k;
    float offy = om[(size_t)(j*2 + 0)*HWF + idx];
    float offx = om[(size_t)(j*2 + 1)*HWF + idx];
    float m = sigmoidf(om[(size_t)(126 + j)*HWF + idx]);
    float ys = (float)(h + (k/3) - 1) + offy;
    float xs = (float)(x + (k%3) - 1) + offx;
    vbuf[(size_t)j*HWF + idx] = bilin(img, ys, xs, IMH, IMW) * m;
  }
}

__global__ __launch_bounds__(256) void deform_out_k(
    const float* __restrict__ vbuf, const float* __restrict__ dcw,
    const float* __restrict__ dcb, float* __restrict__ out)
{
  __shared__ float sw[16*63];
  int idx = blockIdx.x*256 + threadIdx.x;
  int o0 = blockIdx.y*16;
  for (int i = threadIdx.x; i < 16*63; i += 256)
    sw[i] = dcw[(size_t)o0*63 + i];
  __syncthreads();
  float v[63];
  #pragma unroll
  for (int j = 0; j < 63; ++j) v[j] = vbuf[(size_t)j*HWF + idx];
  for (int ol = 0; ol < 16; ++ol){
    float acc = dcb[o0 + ol];
    #pragma unroll
    for (int j = 0; j < 63; ++j) acc += v[j]*sw[ol*63 + j];
    out[(size_t)(o0 + ol)*HWF + idx] = fmaxf(acc, 0.f);
  }
}

extern "C" void kernel_launch(void* const* d_in, const int* in_sizes, int n_in,
                              void* d_out, int out_size, void* d_ws, size_t ws_size,
                              hipStream_t stream)
{
  const float* lqs   = (const float*)d_in[0];
  const float* preds = (const float*)d_in[1];
  const float* mv    = (const float*)d_in[2];
  const float* bw1   = (const float*)d_in[3];
  const float* bb1   = (const float*)d_in[4];
  const float* bw2   = (const float*)d_in[5];
  const float* bb2   = (const float*)d_in[6];
  const float* dn1w  = (const float*)d_in[7];
  const float* dn1b  = (const float*)d_in[8];
  const float* dn2w  = (const float*)d_in[9];
  const float* dn2b  = (const float*)d_in[10];
  const float* up1cw = (const float*)d_in[11];
  const float* up1cb = (const float*)d_in[12];
  const float* up1tw = (const float*)d_in[13];
  const float* up1tb = (const float*)d_in[14];
  const float* up2cw = (const float*)d_in[15];
  const float* up2cb = (const float*)d_in[16];
  const float* up2tw = (const float*)d_in[17];
  const float* up2tb = (const float*)d_in[18];
  const float* trcw  = (const float*)d_in[19];
  const float* trcb  = (const float*)d_in[20];
  const float* trtw  = (const float*)d_in[21];
  const float* trtb  = (const float*)d_in[22];
  const float* ffw   = (const float*)d_in[23];
  const float* ffb   = (const float*)d_in[24];
  const float* omw   = (const float*)d_in[25];
  const float* omb   = (const float*)d_in[26];
  const float* dcw   = (const float*)d_in[27];
  const float* dcb   = (const float*)d_in[28];
  float* outp = (float*)d_out;

  float* ws = (float*)d_ws;
  const size_t NBIG = (size_t)7*64*HWF;
  float* feat = ws;
  float* pred = ws + NBIG;
  float* tmp  = ws + 2*NBIG;
  // overlays on pred region (dead after gate_k)
  float* out0  = pred;
  float* cat1  = pred + 2359296;
  float* cat2  = pred + 3538944;
  float* t0    = pred + 3833856;
  float* u2    = pred + 3870720;
  float* u1    = pred + 4018176;
  float* featf = pred + 4608000;
  float* out1  = cat1 + 64*9216;
  float* out2  = cat2 + 64*2304;
  float* t1    = cat2;
  float* u2t   = cat1;
  // convT packed weights: in tmp region past om output (s dead after fuse, om uses <7M)
  float* wp0 = tmp + 8000000;
  float* wp1 = wp0 + 65536;
  float* wp2 = wp1 + 65536;
  float* vbuf = feat;   // feat dead after fuse

  dim3 blk(256);
  // backbone
  conv3x3_tile<1,0><<<dim3(16,36,7), blk, 0, stream>>>(lqs,   bw1, bb1, tmp,  1, 64, 192, 6);
  conv3x3_tile<4,0><<<dim3(16,36,7), blk, 0, stream>>>(tmp,   bw2, bb2, feat, 64, 64, 192, 6);
  conv3x3_tile<1,0><<<dim3(16,36,7), blk, 0, stream>>>(preds, bw1, bb1, tmp,  1, 64, 192, 6);
  conv3x3_tile<4,0><<<dim3(16,36,7), blk, 0, stream>>>(tmp,   bw2, bb2, pred, 64, 64, 192, 6);
  // gating (+warp) -> s in tmp
  gate_k<<<dim3(144,64,7), blk, 0, stream>>>(feat, pred, mv, tmp);
  // fused dual conv -> out0
  fuse_tile<<<dim3(16,36), blk, 0, stream>>>(tmp, feat, ffw, ffb, out0);
  // prepack convT weights (s in tmp now dead; region past 8M free)
  repack_convT_w<<<dim3(64), blk, 0, stream>>>(trtw,  wp0);
  repack_convT_w<<<dim3(64), blk, 0, stream>>>(up2tw, wp1);
  repack_convT_w<<<dim3(64), blk, 0, stream>>>(up1tw, wp2);
  // U-Net
  conv3x3s2_tile<<<dim3(16,36), blk, 0, stream>>>(out0, dn1w, dn1b, out1, 64, 64, 192, 96, 6);
  conv3x3s2_tile<<<dim3(16,9),  blk, 0, stream>>>(out1, dn2w, dn2b, out2, 64, 64, 96, 48, 3);
  conv3x3s2_tile<<<dim3(16,4),  blk, 0, stream>>>(out2, trcw, trcb, t0,   64, 64, 48, 24, 2);
  convT_tile<<<dim3(4,9),   blk, 0, stream>>>(t0, wp0, trtb, t1, 24, 3);
  conv3x3_tile<4,1><<<dim3(16,4,1), blk, 0, stream>>>(cat2, up2cw, up2cb, u2, 128, 64, 48, 2);
  convT_tile<<<dim3(4,36),  blk, 0, stream>>>(u2, wp1, up2tb, u2t, 48, 6);
  conv3x3_tile<4,1><<<dim3(16,9,1), blk, 0, stream>>>(cat1, up1cw, up1cb, u1, 128, 64, 96, 3);
  convT_tile<<<dim3(4,144), blk, 0, stream>>>(u1, wp2, up1tb, featf, 96, 12);
  // offsets/masks
  conv3x3_tile<4,0><<<dim3(48,36,1), blk, 0, stream>>>(featf, omw, omb, tmp, 64, 189, 192, 6);
  // deformable conv
  deform_sample_k<<<dim3(144,7), blk, 0, stream>>>(lqs, tmp, vbuf);
  deform_out_k<<<dim3(144,4), blk, 0, stream>>>(vbuf, dcw, dcb, outp);
}

// Round 3
// 1666.305 us; speedup vs baseline: 7.7991x; 2.3986x over previous
//
#include <hip/hip_runtime.h>
#include <math.h>

#define IMH 192
#define IMW 192
#define HWF 36864
#define PDIM 194

typedef unsigned short u16t;
typedef __attribute__((ext_vector_type(8))) short short8;
typedef __attribute__((ext_vector_type(4))) float f32x4;

__device__ __forceinline__ float sigmoidf(float x){ return 1.f/(1.f+expf(-x)); }
__device__ __forceinline__ float lrelu(float x){ return x > 0.f ? x : 0.1f*x; }
__device__ __forceinline__ float b2f(u16t h){ unsigned u = ((unsigned)h)<<16; return __uint_as_float(u); }
__device__ __forceinline__ u16t f2b(float f){
  unsigned u = __float_as_uint(f);
  u += 0x7FFFu + ((u>>16)&1u);
  return (u16t)(u>>16);
}

__device__ __forceinline__ float bilin(const float* __restrict__ img, float ys, float xs, int H, int W){
  float y0f = floorf(ys), x0f = floorf(xs);
  float wy = ys - y0f, wx = xs - x0f;
  int y0 = (int)y0f, x0 = (int)x0f;
  float acc = 0.f;
  #pragma unroll
  for (int dy=0; dy<2; ++dy){
    int yi = y0+dy;
    float wyv = dy ? wy : 1.f-wy;
    if (yi < 0 || yi >= H) continue;
    #pragma unroll
    for (int dx=0; dx<2; ++dx){
      int xi = x0+dx;
      float wxv = dx ? wx : 1.f-wx;
      if (xi < 0 || xi >= W) continue;
      acc += img[yi*W+xi]*(wyv*wxv);
    }
  }
  return acc;
}

// ---------- zero the 1-px border of a padded NHWC buffer ----------
__global__ __launch_bounds__(256) void padzero_k(u16t* buf, int C, size_t imgStride){
  int id = blockIdx.x*256 + threadIdx.x;
  int total = 772*C;
  if (id >= total) return;
  int n = blockIdx.y;
  int cell = id / C, c = id % C;
  int r, col;
  if (cell < 194){ r = 0; col = cell; }
  else if (cell < 388){ r = 193; col = cell - 194; }
  else if (cell < 580){ r = cell - 388 + 1; col = 0; }
  else { r = cell - 580 + 1; col = 193; }
  buf[(size_t)n*imgStride + ((size_t)r*PDIM + col)*C + c] = 0;
}

// ---------- pack conv weights (OIHW fp32) into MFMA B-fragment order bf16 ----------
// layout: [tap][kc][nt][lane][8];  c = kc*32 + (lane>>4)*8 + j; o = nt*16 + (lane&15)
__global__ __launch_bounds__(256) void pack_w(const float* __restrict__ w, u16t* __restrict__ pk,
                                              int Cin, int Cout, int NT, int total){
  int id = blockIdx.x*256 + threadIdx.x;
  if (id >= total) return;
  int j = id & 7, l = (id>>3) & 63;
  int r = id >> 9;
  int nt = r % NT; r /= NT;
  int KC = Cin >> 5;
  int kc = r % KC; int tap = r / KC;
  int c = kc*32 + ((l>>4)<<3) + j;
  int o = nt*16 + (l&15);
  float v = (o < Cout) ? w[((size_t)o*Cin + c)*9 + tap] : 0.f;
  pk[id] = f2b(v);
}

// ---------- conv1: 1->64ch 3x3, fp32 math, writes padded NHWC bf16 ----------
__global__ __launch_bounds__(256) void conv1_k(const float* __restrict__ in, const float* __restrict__ w,
                                               const float* __restrict__ bias, u16t* __restrict__ outp){
  __shared__ float sw[576];
  __shared__ float sb[64];
  int tid = threadIdx.x;
  for (int i = tid; i < 576; i += 256) sw[i] = w[i];
  if (tid < 64) sb[tid] = bias[tid];
  __syncthreads();
  int idx = blockIdx.x*256 + tid;
  int n = blockIdx.y;
  int y = idx/IMW, x = idx%IMW;
  const float* ip = in + (size_t)n*HWF;
  float t[9];
  #pragma unroll
  for (int dy = 0; dy < 3; ++dy)
    #pragma unroll
    for (int dx = 0; dx < 3; ++dx){
      int yy = y+dy-1, xx = x+dx-1;
      t[dy*3+dx] = (yy>=0 && yy<IMH && xx>=0 && xx<IMW) ? ip[yy*IMW+xx] : 0.f;
    }
  u16t* op = outp + (size_t)n*(PDIM*PDIM*64) + ((size_t)(y+1)*PDIM + x+1)*64;
  #pragma unroll
  for (int o8 = 0; o8 < 8; ++o8){
    short8 ov;
    #pragma unroll
    for (int j = 0; j < 8; ++j){
      int o = o8*8 + j;
      float acc = sb[o];
      #pragma unroll
      for (int k = 0; k < 9; ++k) acc += t[k]*sw[o*9+k];
      ov[j] = (short)f2b(acc);
    }
    *(short8*)(op + o8*8) = ov;
  }
}

// ---------- MFMA implicit-GEMM 3x3 conv over padded NHWC bf16 ----------
// wave = 16-pixel x-strip (M=16) x Cout(=NT*16). K = 9 taps x KC*32 ch. No LDS.
// OMODE: 0 = NCHW fp32 out; 1 = padded NHWC448 bf16 (choff img*64); 2 = NHWC64 bf16
// STREAMS==2 => fuse epilogue 0.1*lrelu(s)+lrelu(f)
template<int NT, int STREAMS, int OMODE, int KC>
__global__ __launch_bounds__(256) void gconv(
    const u16t* __restrict__ A0, const u16t* __restrict__ A1,
    const u16t* __restrict__ Bp, const float* __restrict__ bias,
    float* __restrict__ outf, u16t* __restrict__ outb,
    int Cout, size_t aImgStride)
{
  const int wave = threadIdx.x >> 6;
  const int lane = threadIdx.x & 63;
  const int sid = blockIdx.x*4 + wave;
  const int y = sid / 12, x0 = (sid % 12) * 16;
  const int img = blockIdx.z;
  const int m = lane & 15, q = lane >> 4;
  const int Cin = KC*32;
  const u16t* a0 = A0 + (size_t)img*aImgStride;
  f32x4 acc[STREAMS][NT];
  #pragma unroll
  for (int s = 0; s < STREAMS; ++s)
    #pragma unroll
    for (int nt = 0; nt < NT; ++nt) acc[s][nt] = (f32x4){0.f,0.f,0.f,0.f};

  for (int tap = 0; tap < 9; ++tap){
    int dy = tap/3, dx = tap%3;
    size_t abase = ((size_t)(y+dy)*PDIM + x0+dx+m)*Cin + q*8;
    const u16t* ap0 = a0 + abase;
    const u16t* ap1 = (STREAMS==2) ? (A1 + abase) : ap0;
    const u16t* bp = Bp + (size_t)(tap*KC)*NT*512 + lane*8;
    #pragma unroll
    for (int kc = 0; kc < KC; ++kc){
      short8 av0 = *(const short8*)(ap0 + kc*32);
      short8 av1;
      if (STREAMS==2) av1 = *(const short8*)(ap1 + kc*32);
      #pragma unroll
      for (int nt = 0; nt < NT; ++nt){
        short8 bv = *(const short8*)(bp + (size_t)(kc*NT + nt)*512);
        acc[0][nt] = __builtin_amdgcn_mfma_f32_16x16x32_bf16(av0, bv, acc[0][nt], 0, 0, 0);
        if (STREAMS==2)
          acc[1][nt] = __builtin_amdgcn_mfma_f32_16x16x32_bf16(av1, bv, acc[1][nt], 0, 0, 0);
      }
    }
  }
  // C/D: col = lane&15 (=out ch), row = (lane>>4)*4 + reg (=pixel in strip)
  const int prow0 = q*4;
  #pragma unroll
  for (int nt = 0; nt < NT; ++nt){
    int o = nt*16 + m;
    if (o >= Cout) continue;
    float bv = bias[o];
    #pragma unroll
    for (int r = 0; r < 4; ++r){
      int prow = prow0 + r;
      float v;
      if (STREAMS==2){
        float v1 = acc[0][nt][r] + bv;
        float v2 = acc[1][nt][r] + bv;
        v = 0.1f*lrelu(v1) + lrelu(v2);
      } else {
        v = acc[0][nt][r] + bv;
      }
      if (OMODE == 0){
        outf[(size_t)o*HWF + (size_t)y*IMW + x0 + prow] = v;
      } else if (OMODE == 1){
        outb[((size_t)(y+1)*PDIM + x0+1+prow)*448 + (size_t)img*64 + o] = f2b(v);
      } else {
        outb[(size_t)img*2359296 + ((size_t)y*IMW + x0+prow)*64 + o] = f2b(v);
      }
    }
  }
}

// ---------- gating + flow-warp, channels-last bf16 ----------
__global__ __launch_bounds__(256) void gate_nhwc(
    const u16t* __restrict__ fpad, const u16t* __restrict__ pred,
    const float* __restrict__ mv, u16t* __restrict__ spad)
{
  int idx = blockIdx.x*256 + threadIdx.x;
  int t = blockIdx.y;
  int y = idx/IMW, x = idx%IMW;
  size_t pc = ((size_t)(y+1)*PDIM + (x+1))*448;
  const u16t* rp = fpad + pc + 192;                 // ref = feat t=3
  const u16t* pp = pred + ((size_t)t*HWF + idx)*64;
  u16t* sp = spad + pc + (size_t)t*64;
  const u16t* tp[4]; float tw[4];
  if (t == 0){
    tp[0] = fpad + pc; tw[0] = 1.f;
    tp[1] = tp[2] = tp[3] = fpad + pc; tw[1] = tw[2] = tw[3] = 0.f;
  } else {
    float fx = mv[(((size_t)(t-1)*HWF + idx))*2 + 0];
    float fy = mv[(((size_t)(t-1)*HWF + idx))*2 + 1];
    float ys = (float)y + fy, xs = (float)x + fx;
    float y0f = floorf(ys), x0f = floorf(xs);
    float wy = ys - y0f, wx = xs - x0f;
    int y0 = (int)y0f, x0i = (int)x0f;
    int k = 0;
    #pragma unroll
    for (int dy2 = 0; dy2 < 2; ++dy2)
      #pragma unroll
      for (int dx2 = 0; dx2 < 2; ++dx2){
        int yi = y0+dy2, xi = x0i+dx2;
        float wv = (dy2 ? wy : 1.f-wy)*(dx2 ? wx : 1.f-wx);
        bool ok = (yi >= 0 && yi <= 191 && xi >= 0 && xi <= 191);
        int yc = min(max(yi,0),191), xc = min(max(xi,0),191);
        tp[k] = fpad + ((size_t)(yc+1)*PDIM + xc+1)*448 + (size_t)(t-1)*64;
        tw[k] = ok ? wv : 0.f;
        ++k;
      }
  }
  #pragma unroll
  for (int c8 = 0; c8 < 8; ++c8){
    short8 rv = *(const short8*)(rp + c8*8);
    short8 pv = *(const short8*)(pp + c8*8);
    short8 t0v = *(const short8*)(tp[0] + c8*8);
    short8 t1v = *(const short8*)(tp[1] + c8*8);
    short8 t2v = *(const short8*)(tp[2] + c8*8);
    short8 t3v = *(const short8*)(tp[3] + c8*8);
    short8 ov;
    #pragma unroll
    for (int j = 0; j < 8; ++j){
      float r = b2f((u16t)rv[j]);
      float p = b2f((u16t)pv[j]);
      float a = tw[0]*b2f((u16t)t0v[j]) + tw[1]*b2f((u16t)t1v[j])
              + tw[2]*b2f((u16t)t2v[j]) + tw[3]*b2f((u16t)t3v[j]);
      float sv = a*sigmoidf(a*r) + p*sigmoidf(p*r);
      ov[j] = (short)f2b(sv);
    }
    *(short8*)(sp + c8*8) = ov;
  }
}

// ---------------- tiled 3x3 stride-1 conv (fp32, for 128-ch up-convs) ----------------
template<int CC, int ACT>
__global__ __launch_bounds__(256) void conv3x3_tile(
    const float* __restrict__ in, const float* __restrict__ w,
    const float* __restrict__ bias, float* __restrict__ out,
    int Cin, int Cout, int H, int tilesX)
{
  __shared__ float sIn[CC][34*35];
  __shared__ float sW[CC][4][9];
  const int W = H;
  const int og = blockIdx.x, tile = blockIdx.y, n = blockIdx.z;
  const int ty0 = (tile/tilesX)*32, tx0 = (tile%tilesX)*32;
  const int o0 = og*4;
  const int tid = threadIdx.x;
  const float* inb = in + (size_t)n*Cin*H*W;
  const int py = 2*(tid>>4), px = 2*(tid&15);
  float acc[4][2][2] = {};
  for (int cb = 0; cb < Cin; cb += CC){
    for (int i = tid; i < CC*36; i += 256){
      int c = i/36, r = i%36, ol = r/9, k = r%9;
      int o = o0 + ol;
      float v = 0.f;
      if (o < Cout && cb + c < Cin) v = w[((size_t)o*Cin + cb + c)*9 + k];
      sW[c][ol][k] = v;
    }
    for (int i = tid; i < CC*1156; i += 256){
      int c = i/1156, rem = i%1156, r = rem/34, col = rem%34;
      int gy = ty0 - 1 + r, gx = tx0 - 1 + col;
      float v = 0.f;
      if (cb + c < Cin && gy >= 0 && gy < H && gx >= 0 && gx < W)
        v = inb[(size_t)(cb + c)*H*W + gy*W + gx];
      sIn[c][r*35 + col] = v;
    }
    __syncthreads();
    #pragma unroll
    for (int c = 0; c < CC; ++c){
      float t[4][4];
      #pragma unroll
      for (int dy = 0; dy < 4; ++dy)
        #pragma unroll
        for (int dx = 0; dx < 4; ++dx) t[dy][dx] = sIn[c][(py+dy)*35 + px+dx];
      #pragma unroll
      for (int ol = 0; ol < 4; ++ol){
        float wv[9];
        #pragma unroll
        for (int k = 0; k < 9; ++k) wv[k] = sW[c][ol][k];
        #pragma unroll
        for (int iy = 0; iy < 2; ++iy)
          #pragma unroll
          for (int ix = 0; ix < 2; ++ix){
            float a = acc[ol][iy][ix];
            #pragma unroll
            for (int dy = 0; dy < 3; ++dy)
              #pragma unroll
              for (int dx = 0; dx < 3; ++dx) a += t[iy+dy][ix+dx]*wv[dy*3+dx];
            acc[ol][iy][ix] = a;
          }
      }
    }
    __syncthreads();
  }
  #pragma unroll
  for (int ol = 0; ol < 4; ++ol){
    int o = o0 + ol;
    if (o >= Cout) continue;
    float b = bias[o];
    #pragma unroll
    for (int iy = 0; iy < 2; ++iy){
      int gy = ty0 + py + iy;
      if (gy >= H) continue;
      #pragma unroll
      for (int ix = 0; ix < 2; ++ix){
        int gx = tx0 + px + ix;
        if (gx >= W) continue;
        float v = acc[ol][iy][ix] + b;
        if (ACT == 1) v = fmaxf(v, 0.f); else if (ACT == 2) v = lrelu(v);
        out[((size_t)n*Cout + o)*(size_t)(H*W) + (size_t)gy*W + gx] = v;
      }
    }
  }
}

// ---------------- tiled 3x3 stride-2 conv (relu) ----------------
__global__ __launch_bounds__(256) void conv3x3s2_tile(
    const float* __restrict__ in, const float* __restrict__ w,
    const float* __restrict__ bias, float* __restrict__ out,
    int Cin, int Cout, int Hin, int Hout, int tilesX)
{
  const int CC = 4;
  __shared__ float sIn[CC][33*35];
  __shared__ float sW[CC][4][9];
  const int Win = Hin, Wout = Hout;
  const int og = blockIdx.x, tile = blockIdx.y;
  const int ty0 = (tile/tilesX)*16, tx0 = (tile%tilesX)*16;
  const int o0 = og*4;
  const int tid = threadIdx.x;
  const int py = tid>>4, px = tid&15;
  float acc[4] = {};
  for (int cb = 0; cb < Cin; cb += CC){
    for (int i = tid; i < CC*36; i += 256){
      int c = i/36, r = i%36, ol = r/9, k = r%9;
      int o = o0 + ol;
      float v = 0.f;
      if (o < Cout) v = w[((size_t)o*Cin + cb + c)*9 + k];
      sW[c][ol][k] = v;
    }
    for (int i = tid; i < CC*1089; i += 256){
      int c = i/1089, rem = i%1089, r = rem/33, col = rem%33;
      int gy = 2*ty0 - 1 + r, gx = 2*tx0 - 1 + col;
      float v = 0.f;
      if (gy >= 0 && gy < Hin && gx >= 0 && gx < Win)
        v = in[(size_t)(cb + c)*Hin*Win + gy*Win + gx];
      sIn[c][r*35 + col] = v;
    }
    __syncthreads();
    #pragma unroll
    for (int c = 0; c < CC; ++c){
      float t[3][3];
      #pragma unroll
      for (int dy = 0; dy < 3; ++dy)
        #pragma unroll
        for (int dx = 0; dx < 3; ++dx) t[dy][dx] = sIn[c][(2*py+dy)*35 + 2*px+dx];
      #pragma unroll
      for (int ol = 0; ol < 4; ++ol){
        float a = acc[ol];
        #pragma unroll
        for (int k = 0; k < 9; ++k) a += t[k/3][k%3]*sW[c][ol][k];
        acc[ol] = a;
      }
    }
    __syncthreads();
  }
  int gy = ty0 + py, gx = tx0 + px;
  if (gy < Hout && gx < Wout){
    #pragma unroll
    for (int ol = 0; ol < 4; ++ol){
      int o = o0 + ol;
      if (o >= Cout) continue;
      float v = fmaxf(acc[ol] + bias[o], 0.f);
      out[(size_t)o*Hout*Wout + (size_t)gy*Wout + gx] = v;
    }
  }
}

// ---------------- convT 4x4 s2 p1 (+relu) ----------------
__global__ __launch_bounds__(256) void repack_convT_w(const float* __restrict__ w, float* __restrict__ wp){
  int id = blockIdx.x*256 + threadIdx.x;
  int par = id >> 12, o = (id >> 6) & 63, i = id & 63;
  int ry = par >> 1, rx = par & 1;
  #pragma unroll
  for (int jy = 0; jy < 2; ++jy)
    #pragma unroll
    for (int jx = 0; jx < 2; ++jx){
      int ka = 3 - ry - 2*jy, kb = 3 - rx - 2*jx;
      wp[((size_t)((par*64 + o)*64 + i))*4 + jy*2 + jx] = w[((size_t)(i*64 + o))*16 + ka*4 + kb];
    }
}

template<int OUTB>
__global__ __launch_bounds__(256) void convT_tile(
    const float* __restrict__ in, const float* __restrict__ wp,
    const float* __restrict__ bias, float* __restrict__ out,
    u16t* __restrict__ outb, int Hin, int tilesX)
{
  const int CC = 4;
  __shared__ float sIn[CC][10*11];
  __shared__ float sW[16][CC][4][4];
  const int Win = Hin, Hout = 2*Hin, Wout = 2*Hin;
  const int o0 = blockIdx.x*16;
  const int tile = blockIdx.y;
  const int ty0 = (tile/tilesX)*16, tx0 = (tile%tilesX)*16;
  const int tid = threadIdx.x;
  const int py = tid>>4, px = tid&15;
  const int ry = py&1, rx = px&1, par = ry*2 + rx;
  const int lr = py>>1, lc = px>>1;
  const int r0 = ty0>>1, c0 = tx0>>1;
  float acc[16] = {};
  for (int ib = 0; ib < 64; ib += CC){
    for (int i = tid; i < CC*100; i += 256){
      int c = i/100, rem = i%100, r = rem/10, col = rem%10;
      int gy = r0 - 1 + r, gx = c0 - 1 + col;
      float v = 0.f;
      if (gy >= 0 && gy < Hin && gx >= 0 && gx < Win)
        v = in[(size_t)(ib + c)*Hin*Win + gy*Win + gx];
      sIn[c][r*11 + col] = v;
    }
    for (int i = tid; i < 1024; i += 256){
      int ol = i >> 6, rem = i & 63, ci = rem >> 4, p2 = (rem >> 2) & 3, j = rem & 3;
      sW[ol][ci][p2][j] = wp[((size_t)((p2*64 + o0 + ol)*64) + ib + ci)*4 + j];
    }
    __syncthreads();
    #pragma unroll
    for (int ci = 0; ci < CC; ++ci){
      int rb = lr + ry, cb = lc + rx;
      float t00 = sIn[ci][rb*11 + cb],     t01 = sIn[ci][rb*11 + cb + 1];
      float t10 = sIn[ci][(rb+1)*11 + cb], t11 = sIn[ci][(rb+1)*11 + cb + 1];
      #pragma unroll
      for (int ol = 0; ol < 16; ++ol){
        const float* wv = &sW[ol][ci][par][0];
        acc[ol] += t00*wv[0] + t01*wv[1] + t10*wv[2] + t11*wv[3];
      }
    }
    __syncthreads();
  }
  int gy = ty0 + py, gx = tx0 + px;
  if (OUTB){
    u16t* op = outb + ((size_t)(gy+1)*PDIM + gx+1)*64 + o0;
    short8 pa, pb;
    #pragma unroll
    for (int i = 0; i < 8; ++i) pa[i] = (short)f2b(fmaxf(acc[i] + bias[o0+i], 0.f));
    #pragma unroll
    for (int i = 0; i < 8; ++i) pb[i] = (short)f2b(fmaxf(acc[8+i] + bias[o0+8+i], 0.f));
    *(short8*)op = pa;
    *(short8*)(op + 8) = pb;
  } else {
    #pragma unroll
    for (int ol = 0; ol < 16; ++ol){
      int o = o0 + ol;
      out[(size_t)o*Hout*Wout + (size_t)gy*Wout + gx] = fmaxf(acc[ol] + bias[o], 0.f);
    }
  }
}

// ---------------- deformable conv ----------------
__global__ __launch_bounds__(256) void deform_sample_k(
    const float* __restrict__ lqs, const float* __restrict__ om,
    float* __restrict__ vbuf)
{
  int idx = blockIdx.x*256 + threadIdx.x;
  int g = blockIdx.y;
  int h = idx / IMW, x = idx % IMW;
  const float* img = lqs + (size_t)g*HWF;
  #pragma unroll
  for (int k = 0; k < 9; ++k){
    int j = g*9 + k;
    float offy = om[(size_t)(j*2 + 0)*HWF + idx];
    float offx = om[(size_t)(j*2 + 1)*HWF + idx];
    float m = sigmoidf(om[(size_t)(126 + j)*HWF + idx]);
    float ys = (float)(h + (k/3) - 1) + offy;
    float xs = (float)(x + (k%3) - 1) + offx;
    vbuf[(size_t)j*HWF + idx] = bilin(img, ys, xs, IMH, IMW) * m;
  }
}

__global__ __launch_bounds__(256) void deform_out_k(
    const float* __restrict__ vbuf, const float* __restrict__ dcw,
    const float* __restrict__ dcb, float* __restrict__ out)
{
  __shared__ float sw[16*63];
  int idx = blockIdx.x*256 + threadIdx.x;
  int o0 = blockIdx.y*16;
  for (int i = threadIdx.x; i < 16*63; i += 256)
    sw[i] = dcw[(size_t)o0*63 + i];
  __syncthreads();
  float v[63];
  #pragma unroll
  for (int j = 0; j < 63; ++j) v[j] = vbuf[(size_t)j*HWF + idx];
  for (int ol = 0; ol < 16; ++ol){
    float acc = dcb[o0 + ol];
    #pragma unroll
    for (int j = 0; j < 63; ++j) acc += v[j]*sw[ol*63 + j];
    out[(size_t)(o0 + ol)*HWF + idx] = fmaxf(acc, 0.f);
  }
}

extern "C" void kernel_launch(void* const* d_in, const int* in_sizes, int n_in,
                              void* d_out, int out_size, void* d_ws, size_t ws_size,
                              hipStream_t stream)
{
  const float* lqs   = (const float*)d_in[0];
  const float* preds = (const float*)d_in[1];
  const float* mv    = (const float*)d_in[2];
  const float* bw1   = (const float*)d_in[3];
  const float* bb1   = (const float*)d_in[4];
  const float* bw2   = (const float*)d_in[5];
  const float* bb2   = (const float*)d_in[6];
  const float* dn1w  = (const float*)d_in[7];
  const float* dn1b  = (const float*)d_in[8];
  const float* dn2w  = (const float*)d_in[9];
  const float* dn2b  = (const float*)d_in[10];
  const float* up1cw = (const float*)d_in[11];
  const float* up1cb = (const float*)d_in[12];
  const float* up1tw = (const float*)d_in[13];
  const float* up1tb = (const float*)d_in[14];
  const float* up2cw = (const float*)d_in[15];
  const float* up2cb = (const float*)d_in[16];
  const float* up2tw = (const float*)d_in[17];
  const float* up2tb = (const float*)d_in[18];
  const float* trcw  = (const float*)d_in[19];
  const float* trcb  = (const float*)d_in[20];
  const float* trtw  = (const float*)d_in[21];
  const float* trtb  = (const float*)d_in[22];
  const float* ffw   = (const float*)d_in[23];
  const float* ffb   = (const float*)d_in[24];
  const float* omw   = (const float*)d_in[25];
  const float* omb   = (const float*)d_in[26];
  const float* dcw   = (const float*)d_in[27];
  const float* dcb   = (const float*)d_in[28];
  float* outp = (float*)d_out;

  char* base = (char*)d_ws;
  const size_t PIMG64 = (size_t)PDIM*PDIM*64;          // 2,408,704 elems
  const size_t SZ_BB   = 7*PIMG64*2;                   // 33,721,856 B
  const size_t SZ_FPAD = (size_t)PDIM*PDIM*448*2;      // 33,721,856 B
  const size_t SZ_PRED = (size_t)7*HWF*64*2;           // 33,030,144 B
  u16t* bbpad    = (u16t*)base;                                  // conv1 out; later: spad; later: featfpad
  u16t* fpad     = (u16t*)(base + SZ_BB);                        // feat NHWC448 padded; later: vbuf (fp32)
  u16t* prednhwc = (u16t*)(base + SZ_BB + SZ_FPAD);              // pred NHWC64; later: om NCHW fp32
  float* fA      = (float*)(base + SZ_BB + SZ_FPAD + SZ_PRED);   // out0 + U-Net smalls (4,608,000 f)
  char* pk       = base + SZ_BB + SZ_FPAD + SZ_PRED + 4608000*sizeof(float);
  u16t* ffwpack = (u16t*)pk;                 // 258048 elems
  u16t* c2pack  = (u16t*)(pk + 516096);      // 36864
  u16t* ompack  = (u16t*)(pk + 589824);      // 110592
  float* wp0    = (float*)(pk + 811008);     // 65536 f
  float* wp1    = wp0 + 65536;
  float* wp2    = wp1 + 65536;

  u16t* spad = bbpad;          // [194][194][448] after conv2-pred done
  u16t* featfpad = bbpad;      // [194][194][64] after fuse done
  float* om = (float*)prednhwc;
  float* vbuf = (float*)fpad;

  float* out0 = fA;                    // 64*36864
  float* cat1 = fA + 2359296;          // [u2t | out1]
  float* cat2 = fA + 3538944;          // [t1 | out2]
  float* t0   = fA + 3833856;
  float* u2   = fA + 3870720;
  float* u1   = fA + 4018176;
  float* out1 = cat1 + 589824;
  float* out2 = cat2 + 147456;
  float* t1   = cat2;
  float* u2t  = cat1;

  dim3 blk(256);
  // weight packs
  pack_w<<<dim3(1008), blk, 0, stream>>>(ffw, ffwpack, 448, 64, 4, 258048);
  pack_w<<<dim3(144),  blk, 0, stream>>>(bw2, c2pack, 64, 64, 4, 36864);
  pack_w<<<dim3(432),  blk, 0, stream>>>(omw, ompack, 64, 189, 12, 110592);
  repack_convT_w<<<dim3(64), blk, 0, stream>>>(trtw,  wp0);
  repack_convT_w<<<dim3(64), blk, 0, stream>>>(up2tw, wp1);
  repack_convT_w<<<dim3(64), blk, 0, stream>>>(up1tw, wp2);
  // pad borders
  padzero_k<<<dim3(194,7), blk, 0, stream>>>(bbpad, 64, PIMG64);
  padzero_k<<<dim3(1352,1), blk, 0, stream>>>(fpad, 448, 0);
  // backbone lqs -> fpad (NHWC448 bf16 padded)
  conv1_k<<<dim3(144,7), blk, 0, stream>>>(lqs, bw1, bb1, bbpad);
  gconv<4,1,1,2><<<dim3(576,1,7), blk, 0, stream>>>(bbpad, nullptr, c2pack, bb2, nullptr, fpad, 64, PIMG64);
  // backbone preds -> prednhwc (NHWC64 bf16)
  conv1_k<<<dim3(144,7), blk, 0, stream>>>(preds, bw1, bb1, bbpad);
  gconv<4,1,2,2><<<dim3(576,1,7), blk, 0, stream>>>(bbpad, nullptr, c2pack, bb2, nullptr, prednhwc, 64, PIMG64);
  // gate (+warp) -> spad (reuses bbpad region)
  padzero_k<<<dim3(1352,1), blk, 0, stream>>>(spad, 448, 0);
  gate_nhwc<<<dim3(144,7), blk, 0, stream>>>(fpad, prednhwc, mv, spad);
  // fused dual conv -> out0 (NCHW fp32)
  gconv<4,2,0,14><<<dim3(576,1,1), blk, 0, stream>>>(spad, fpad, ffwpack, ffb, out0, nullptr, 64, 0);
  // U-Net (fp32)
  conv3x3s2_tile<<<dim3(16,36), blk, 0, stream>>>(out0, dn1w, dn1b, out1, 64, 64, 192, 96, 6);
  conv3x3s2_tile<<<dim3(16,9),  blk, 0, stream>>>(out1, dn2w, dn2b, out2, 64, 64, 96, 48, 3);
  conv3x3s2_tile<<<dim3(16,4),  blk, 0, stream>>>(out2, trcw, trcb, t0,   64, 64, 48, 24, 2);
  convT_tile<0><<<dim3(4,9),   blk, 0, stream>>>(t0, wp0, trtb, t1, nullptr, 24, 3);
  conv3x3_tile<4,1><<<dim3(16,4,1), blk, 0, stream>>>(cat2, up2cw, up2cb, u2, 128, 64, 48, 2);
  convT_tile<0><<<dim3(4,36),  blk, 0, stream>>>(u2, wp1, up2tb, u2t, nullptr, 48, 6);
  conv3x3_tile<4,1><<<dim3(16,9,1), blk, 0, stream>>>(cat1, up1cw, up1cb, u1, 128, 64, 96, 3);
  // final convT writes featfpad (bf16 NHWC64 padded; reuses bbpad region)
  padzero_k<<<dim3(194,1), blk, 0, stream>>>(featfpad, 64, 0);
  convT_tile<1><<<dim3(4,144), blk, 0, stream>>>(u1, wp2, up1tb, nullptr, featfpad, 96, 12);
  // offsets/masks conv (64 -> 189) -> om (NCHW fp32, reuses prednhwc region)
  gconv<12,1,0,2><<<dim3(576,1,1), blk, 0, stream>>>(featfpad, nullptr, ompack, omb, om, nullptr, 189, 0);
  // deformable conv
  deform_sample_k<<<dim3(144,7), blk, 0, stream>>>(lqs, om, vbuf);
  deform_out_k<<<dim3(144,4), blk, 0, stream>>>(vbuf, dcw, dcb, outp);
}

// Round 4
// 938.367 us; speedup vs baseline: 13.8493x; 1.7758x over previous
//
#include <hip/hip_runtime.h>
#include <math.h>

#define IMH 192
#define IMW 192
#define HWF 36864
#define PDIM 194

typedef unsigned short u16t;
typedef __attribute__((ext_vector_type(8))) short short8;
typedef __attribute__((ext_vector_type(4))) float f32x4;

__device__ __forceinline__ float sigmoidf(float x){ return 1.f/(1.f+expf(-x)); }
__device__ __forceinline__ float lrelu(float x){ return x > 0.f ? x : 0.1f*x; }
__device__ __forceinline__ float b2f(u16t h){ unsigned u = ((unsigned)h)<<16; return __uint_as_float(u); }
__device__ __forceinline__ u16t f2b(float f){
  unsigned u = __float_as_uint(f);
  u += 0x7FFFu + ((u>>16)&1u);
  return (u16t)(u>>16);
}

__device__ __forceinline__ float bilin(const float* __restrict__ img, float ys, float xs, int H, int W){
  float y0f = floorf(ys), x0f = floorf(xs);
  float wy = ys - y0f, wx = xs - x0f;
  int y0 = (int)y0f, x0 = (int)x0f;
  float acc = 0.f;
  #pragma unroll
  for (int dy=0; dy<2; ++dy){
    int yi = y0+dy;
    float wyv = dy ? wy : 1.f-wy;
    if (yi < 0 || yi >= H) continue;
    #pragma unroll
    for (int dx=0; dx<2; ++dx){
      int xi = x0+dx;
      float wxv = dx ? wx : 1.f-wx;
      if (xi < 0 || xi >= W) continue;
      acc += img[yi*W+xi]*(wyv*wxv);
    }
  }
  return acc;
}

// ---------- zero the 1-px border of a dim x dim x C padded NHWC buffer ----------
__global__ __launch_bounds__(256) void padzero2(u16t* buf, int C, int dim, size_t imgStride){
  int n = blockIdx.y;
  int total = (4*dim - 4)*C;
  for (int id = blockIdx.x*256 + threadIdx.x; id < total; id += gridDim.x*256){
    int cell = id / C, c = id % C;
    int d2 = dim - 1;
    int r, col;
    if (cell < dim){ r = 0; col = cell; }
    else if (cell < 2*dim){ r = d2; col = cell - dim; }
    else if (cell < 3*dim - 2){ r = cell - 2*dim + 1; col = 0; }
    else { r = cell - (3*dim - 2) + 1; col = d2; }
    buf[(size_t)n*imgStride + ((size_t)r*dim + col)*C + c] = 0;
  }
}

// ---------- pack conv weights (OIHW fp32) into MFMA B-fragment order bf16 ----------
// layout: [tap][kc][nt][lane][8];  c = kc*32 + (lane>>4)*8 + j; o = nt*16 + (lane&15)
__global__ __launch_bounds__(256) void pack_w(const float* __restrict__ w, u16t* __restrict__ pk,
                                              int Cin, int Cout, int NT, int total){
  int id = blockIdx.x*256 + threadIdx.x;
  if (id >= total) return;
  int j = id & 7, l = (id>>3) & 63;
  int r = id >> 9;
  int nt = r % NT; r /= NT;
  int KC = Cin >> 5;
  int kc = r % KC; int tap = r / KC;
  int c = kc*32 + ((l>>4)<<3) + j;
  int o = nt*16 + (l&15);
  float v = (o < Cout) ? w[((size_t)o*Cin + c)*9 + tap] : 0.f;
  pk[id] = f2b(v);
}

// ---------- conv1: 1->64ch 3x3, fp32 math, writes padded NHWC bf16 ----------
__global__ __launch_bounds__(256) void conv1_k(const float* __restrict__ in, const float* __restrict__ w,
                                               const float* __restrict__ bias, u16t* __restrict__ outp){
  __shared__ float sw[576];
  __shared__ float sb[64];
  int tid = threadIdx.x;
  for (int i = tid; i < 576; i += 256) sw[i] = w[i];
  if (tid < 64) sb[tid] = bias[tid];
  __syncthreads();
  int idx = blockIdx.x*256 + tid;
  int n = blockIdx.y;
  int y = idx/IMW, x = idx%IMW;
  const float* ip = in + (size_t)n*HWF;
  float t[9];
  #pragma unroll
  for (int dy = 0; dy < 3; ++dy)
    #pragma unroll
    for (int dx = 0; dx < 3; ++dx){
      int yy = y+dy-1, xx = x+dx-1;
      t[dy*3+dx] = (yy>=0 && yy<IMH && xx>=0 && xx<IMW) ? ip[yy*IMW+xx] : 0.f;
    }
  u16t* op = outp + (size_t)n*(PDIM*PDIM*64) + ((size_t)(y+1)*PDIM + x+1)*64;
  #pragma unroll
  for (int o8 = 0; o8 < 8; ++o8){
    short8 ov;
    #pragma unroll
    for (int j = 0; j < 8; ++j){
      int o = o8*8 + j;
      float acc = sb[o];
      #pragma unroll
      for (int k = 0; k < 9; ++k) acc += t[k]*sw[o*9+k];
      ov[j] = (short)f2b(acc);
    }
    *(short8*)(op + o8*8) = ov;
  }
}

// ---------- generalized MFMA implicit-GEMM 3x3 conv over padded NHWC bf16 ----------
// wave = 16-out-pixel x-strip (M=16) x Cout(=NT*16). K = 9 taps x KC*32 ch. No LDS.
// STRIDE: conv stride (1 or 2). OMODE: 0 = NCHW fp32 (img-major); 1 = bf16 NHWC padded(+1 border);
// 2 = bf16 NHWC tight. STREAMS==2 => fuse epilogue 0.1*lrelu(s)+lrelu(f). ACT: relu for 1-stream.
template<int NT, int STREAMS, int KC, int STRIDE, int OMODE, int ACT>
__global__ __launch_bounds__(256) void gconv2(
    const u16t* __restrict__ A0, const u16t* __restrict__ A1,
    const u16t* __restrict__ Bp, const float* __restrict__ bias,
    float* __restrict__ outf, u16t* __restrict__ outb,
    int Cout, int Wout, int strips,
    int pitchIn, int csIn, int coIn, size_t aImgStride,
    size_t outImgStride, int pitchOut, int csOut, int coOut)
{
  const int wave = threadIdx.x >> 6;
  const int lane = threadIdx.x & 63;
  const int sid = blockIdx.x*4 + wave;
  const int y = sid / strips, xs = (sid % strips) * 16;
  const int img = blockIdx.z;
  const int m = lane & 15, q = lane >> 4;
  f32x4 acc[STREAMS][NT];
  #pragma unroll
  for (int s = 0; s < STREAMS; ++s)
    #pragma unroll
    for (int nt = 0; nt < NT; ++nt) acc[s][nt] = (f32x4){0.f,0.f,0.f,0.f};

  for (int tap = 0; tap < 9; ++tap){
    int dy = tap/3, dx = tap%3;
    int row = STRIDE*y + dy;
    int col = (STRIDE == 1) ? (xs + m + dx) : (2*(xs + m) + dx);
    size_t abase = (size_t)img*aImgStride + ((size_t)row*pitchIn + col)*csIn + coIn + q*8;
    const u16t* ap0 = A0 + abase;
    const u16t* ap1 = (STREAMS==2) ? (A1 + abase) : ap0;
    const u16t* bp = Bp + (size_t)(tap*KC)*NT*512 + lane*8;
    #pragma unroll
    for (int kc = 0; kc < KC; ++kc){
      short8 av0 = *(const short8*)(ap0 + kc*32);
      short8 av1;
      if (STREAMS==2) av1 = *(const short8*)(ap1 + kc*32);
      #pragma unroll
      for (int nt = 0; nt < NT; ++nt){
        short8 bv = *(const short8*)(bp + (size_t)(kc*NT + nt)*512);
        acc[0][nt] = __builtin_amdgcn_mfma_f32_16x16x32_bf16(av0, bv, acc[0][nt], 0, 0, 0);
        if (STREAMS==2)
          acc[1][nt] = __builtin_amdgcn_mfma_f32_16x16x32_bf16(av1, bv, acc[1][nt], 0, 0, 0);
      }
    }
  }
  // C/D: col = lane&15 (=out ch), row = (lane>>4)*4 + reg (=pixel in strip)
  const int prow0 = q*4;
  #pragma unroll
  for (int nt = 0; nt < NT; ++nt){
    int o = nt*16 + m;
    if (o >= Cout) continue;
    float bv = bias[o];
    #pragma unroll
    for (int r = 0; r < 4; ++r){
      int px = xs + prow0 + r;
      if (px >= Wout) continue;
      float v;
      if (STREAMS==2){
        v = 0.1f*lrelu(acc[0][nt][r] + bv) + lrelu(acc[1][nt][r] + bv);
      } else {
        v = acc[0][nt][r] + bv;
        if (ACT) v = fmaxf(v, 0.f);
      }
      if (OMODE == 0){
        outf[((size_t)img*Cout + o)*((size_t)Wout*Wout) + (size_t)y*Wout + px] = v;
      } else if (OMODE == 1){
        outb[(size_t)img*outImgStride + ((size_t)(y+1)*pitchOut + px+1)*csOut + coOut + o] = f2b(v);
      } else {
        outb[(size_t)img*outImgStride + ((size_t)y*pitchOut + px)*csOut + coOut + o] = f2b(v);
      }
    }
  }
}

// ---------- gating + flow-warp, channels-last bf16 ----------
__global__ __launch_bounds__(256) void gate_nhwc(
    const u16t* __restrict__ fpad, const u16t* __restrict__ pred,
    const float* __restrict__ mv, u16t* __restrict__ spad)
{
  int idx = blockIdx.x*256 + threadIdx.x;
  int t = blockIdx.y;
  int y = idx/IMW, x = idx%IMW;
  size_t pc = ((size_t)(y+1)*PDIM + (x+1))*448;
  const u16t* rp = fpad + pc + 192;                 // ref = feat t=3
  const u16t* pp = pred + ((size_t)t*HWF + idx)*64;
  u16t* sp = spad + pc + (size_t)t*64;
  const u16t* tp[4]; float tw[4];
  if (t == 0){
    tp[0] = fpad + pc; tw[0] = 1.f;
    tp[1] = tp[2] = tp[3] = fpad + pc; tw[1] = tw[2] = tw[3] = 0.f;
  } else {
    float fx = mv[(((size_t)(t-1)*HWF + idx))*2 + 0];
    float fy = mv[(((size_t)(t-1)*HWF + idx))*2 + 1];
    float ys = (float)y + fy, xs = (float)x + fx;
    float y0f = floorf(ys), x0f = floorf(xs);
    float wy = ys - y0f, wx = xs - x0f;
    int y0 = (int)y0f, x0i = (int)x0f;
    int k = 0;
    #pragma unroll
    for (int dy2 = 0; dy2 < 2; ++dy2)
      #pragma unroll
      for (int dx2 = 0; dx2 < 2; ++dx2){
        int yi = y0+dy2, xi = x0i+dx2;
        float wv = (dy2 ? wy : 1.f-wy)*(dx2 ? wx : 1.f-wx);
        bool ok = (yi >= 0 && yi <= 191 && xi >= 0 && xi <= 191);
        int yc = min(max(yi,0),191), xc = min(max(xi,0),191);
        tp[k] = fpad + ((size_t)(yc+1)*PDIM + xc+1)*448 + (size_t)(t-1)*64;
        tw[k] = ok ? wv : 0.f;
        ++k;
      }
  }
  #pragma unroll
  for (int c8 = 0; c8 < 8; ++c8){
    short8 rv = *(const short8*)(rp + c8*8);
    short8 pv = *(const short8*)(pp + c8*8);
    short8 t0v = *(const short8*)(tp[0] + c8*8);
    short8 t1v = *(const short8*)(tp[1] + c8*8);
    short8 t2v = *(const short8*)(tp[2] + c8*8);
    short8 t3v = *(const short8*)(tp[3] + c8*8);
    short8 ov;
    #pragma unroll
    for (int j = 0; j < 8; ++j){
      float r = b2f((u16t)rv[j]);
      float p = b2f((u16t)pv[j]);
      float a = tw[0]*b2f((u16t)t0v[j]) + tw[1]*b2f((u16t)t1v[j])
              + tw[2]*b2f((u16t)t2v[j]) + tw[3]*b2f((u16t)t3v[j]);
      float sv = a*sigmoidf(a*r) + p*sigmoidf(p*r);
      ov[j] = (short)f2b(sv);
    }
    *(short8*)(sp + c8*8) = ov;
  }
}

// ---------------- convT 4x4 s2 p1 (+relu): parity-decomposed, fp32 in, bf16 NHWC out ----------------
__global__ __launch_bounds__(256) void repack_convT_w(const float* __restrict__ w, float* __restrict__ wp){
  int id = blockIdx.x*256 + threadIdx.x;
  int par = id >> 12, o = (id >> 6) & 63, i = id & 63;
  int ry = par >> 1, rx = par & 1;
  #pragma unroll
  for (int jy = 0; jy < 2; ++jy)
    #pragma unroll
    for (int jx = 0; jx < 2; ++jx){
      int ka = 3 - ry - 2*jy, kb = 3 - rx - 2*jx;
      wp[((size_t)((par*64 + o)*64 + i))*4 + jy*2 + jx] = w[((size_t)(i*64 + o))*16 + ka*4 + kb];
    }
}

__global__ __launch_bounds__(256) void convT_tile2(
    const float* __restrict__ in, const float* __restrict__ wp,
    const float* __restrict__ bias, u16t* __restrict__ outb,
    int Hin, int tilesX, int pitchOut, int csOut, int coOut)
{
  const int CC = 4;
  __shared__ float sIn[CC][10*11];
  __shared__ float sW[16][CC][4][4];
  const int Win = Hin;
  const int o0 = blockIdx.x*16;
  const int tile = blockIdx.y;
  const int ty0 = (tile/tilesX)*16, tx0 = (tile%tilesX)*16;
  const int tid = threadIdx.x;
  const int py = tid>>4, px = tid&15;
  const int ry = py&1, rx = px&1, par = ry*2 + rx;
  const int lr = py>>1, lc = px>>1;
  const int r0 = ty0>>1, c0 = tx0>>1;
  float acc[16] = {};
  for (int ib = 0; ib < 64; ib += CC){
    for (int i = tid; i < CC*100; i += 256){
      int c = i/100, rem = i%100, r = rem/10, col = rem%10;
      int gy = r0 - 1 + r, gx = c0 - 1 + col;
      float v = 0.f;
      if (gy >= 0 && gy < Hin && gx >= 0 && gx < Win)
        v = in[(size_t)(ib + c)*Hin*Win + gy*Win + gx];
      sIn[c][r*11 + col] = v;
    }
    for (int i = tid; i < 1024; i += 256){
      int ol = i >> 6, rem = i & 63, ci = rem >> 4, p2 = (rem >> 2) & 3, j = rem & 3;
      sW[ol][ci][p2][j] = wp[((size_t)((p2*64 + o0 + ol)*64) + ib + ci)*4 + j];
    }
    __syncthreads();
    #pragma unroll
    for (int ci = 0; ci < CC; ++ci){
      int rb = lr + ry, cb = lc + rx;
      float t00 = sIn[ci][rb*11 + cb],     t01 = sIn[ci][rb*11 + cb + 1];
      float t10 = sIn[ci][(rb+1)*11 + cb], t11 = sIn[ci][(rb+1)*11 + cb + 1];
      #pragma unroll
      for (int ol = 0; ol < 16; ++ol){
        const float* wv = &sW[ol][ci][par][0];
        acc[ol] += t00*wv[0] + t01*wv[1] + t10*wv[2] + t11*wv[3];
      }
    }
    __syncthreads();
  }
  int gy = ty0 + py, gx = tx0 + px;
  u16t* op = outb + ((size_t)(gy+1)*pitchOut + gx+1)*csOut + coOut + o0;
  short8 pa, pb;
  #pragma unroll
  for (int i = 0; i < 8; ++i) pa[i] = (short)f2b(fmaxf(acc[i] + bias[o0+i], 0.f));
  #pragma unroll
  for (int i = 0; i < 8; ++i) pb[i] = (short)f2b(fmaxf(acc[8+i] + bias[o0+8+i], 0.f));
  *(short8*)op = pa;
  *(short8*)(op + 8) = pb;
}

// ---------------- deformable conv ----------------
__global__ __launch_bounds__(256) void deform_sample_k(
    const float* __restrict__ lqs, const float* __restrict__ om,
    float* __restrict__ vbuf)
{
  int idx = blockIdx.x*256 + threadIdx.x;
  int g = blockIdx.y;
  int h = idx / IMW, x = idx % IMW;
  const float* img = lqs + (size_t)g*HWF;
  #pragma unroll
  for (int k = 0; k < 9; ++k){
    int j = g*9 + k;
    float offy = om[(size_t)(j*2 + 0)*HWF + idx];
    float offx = om[(size_t)(j*2 + 1)*HWF + idx];
    float m = sigmoidf(om[(size_t)(126 + j)*HWF + idx]);
    float ys = (float)(h + (k/3) - 1) + offy;
    float xs = (float)(x + (k%3) - 1) + offx;
    vbuf[(size_t)j*HWF + idx] = bilin(img, ys, xs, IMH, IMW) * m;
  }
}

__global__ __launch_bounds__(256) void deform_out_k(
    const float* __restrict__ vbuf, const float* __restrict__ dcw,
    const float* __restrict__ dcb, float* __restrict__ out)
{
  __shared__ float sw[16*63];
  int idx = blockIdx.x*256 + threadIdx.x;
  int o0 = blockIdx.y*16;
  for (int i = threadIdx.x; i < 16*63; i += 256)
    sw[i] = dcw[(size_t)o0*63 + i];
  __syncthreads();
  float v[63];
  #pragma unroll
  for (int j = 0; j < 63; ++j) v[j] = vbuf[(size_t)j*HWF + idx];
  for (int ol = 0; ol < 16; ++ol){
    float acc = dcb[o0 + ol];
    #pragma unroll
    for (int j = 0; j < 63; ++j) acc += v[j]*sw[ol*63 + j];
    out[(size_t)(o0 + ol)*HWF + idx] = fmaxf(acc, 0.f);
  }
}

extern "C" void kernel_launch(void* const* d_in, const int* in_sizes, int n_in,
                              void* d_out, int out_size, void* d_ws, size_t ws_size,
                              hipStream_t stream)
{
  const float* lqs   = (const float*)d_in[0];
  const float* preds = (const float*)d_in[1];
  const float* mv    = (const float*)d_in[2];
  const float* bw1   = (const float*)d_in[3];
  const float* bb1   = (const float*)d_in[4];
  const float* bw2   = (const float*)d_in[5];
  const float* bb2   = (const float*)d_in[6];
  const float* dn1w  = (const float*)d_in[7];
  const float* dn1b  = (const float*)d_in[8];
  const float* dn2w  = (const float*)d_in[9];
  const float* dn2b  = (const float*)d_in[10];
  const float* up1cw = (const float*)d_in[11];
  const float* up1cb = (const float*)d_in[12];
  const float* up1tw = (const float*)d_in[13];
  const float* up1tb = (const float*)d_in[14];
  const float* up2cw = (const float*)d_in[15];
  const float* up2cb = (const float*)d_in[16];
  const float* up2tw = (const float*)d_in[17];
  const float* up2tb = (const float*)d_in[18];
  const float* trcw  = (const float*)d_in[19];
  const float* trcb  = (const float*)d_in[20];
  const float* trtw  = (const float*)d_in[21];
  const float* trtb  = (const float*)d_in[22];
  const float* ffw   = (const float*)d_in[23];
  const float* ffb   = (const float*)d_in[24];
  const float* omw   = (const float*)d_in[25];
  const float* omb   = (const float*)d_in[26];
  const float* dcw   = (const float*)d_in[27];
  const float* dcb   = (const float*)d_in[28];
  float* outp = (float*)d_out;

  char* p = (char*)d_ws;
  const size_t PIMG64 = (size_t)PDIM*PDIM*64;
  u16t* bbpad    = (u16t*)p; p += 7*PIMG64*2;                 // conv1 out; later spad; later featfpad
  u16t* fpad     = (u16t*)p; p += (size_t)PDIM*PDIM*448*2;    // feat NHWC448; later vbuf (fp32)
  u16t* prednhwc = (u16t*)p; p += (size_t)7*HWF*64*2;         // pred NHWC64; later om (fp32)
  u16t* out0pad  = (u16t*)p; p += (size_t)PDIM*PDIM*64*2;     // fuse out, padded NHWC64
  u16t* cat1pad  = (u16t*)p; p += (size_t)98*98*128*2;        // [u2t | out1], padded NHWC128
  u16t* cat2pad  = (u16t*)p; p += (size_t)50*50*128*2;        // [t1 | out2], padded NHWC128
  float* t0      = (float*)p; p += (size_t)24*24*64*4;
  float* u2      = (float*)p; p += (size_t)48*48*64*4;
  float* u1      = (float*)p; p += (size_t)96*96*64*4;
  u16t* ffwpack  = (u16t*)p; p += 258048*2;
  u16t* c2pack   = (u16t*)p; p += 36864*2;
  u16t* ompack   = (u16t*)p; p += 110592*2;
  u16t* dn1pack  = (u16t*)p; p += 36864*2;
  u16t* dn2pack  = (u16t*)p; p += 36864*2;
  u16t* trcpack  = (u16t*)p; p += 36864*2;
  u16t* up2cpack = (u16t*)p; p += 73728*2;
  u16t* up1cpack = (u16t*)p; p += 73728*2;
  float* wp0     = (float*)p; p += 65536*4;
  float* wp1     = (float*)p; p += 65536*4;
  float* wp2     = (float*)p; p += 65536*4;

  u16t* spad = bbpad;         // [194][194][448] after backbone done
  u16t* featfpad = bbpad;     // [194][194][64] after fuse done
  float* om = (float*)prednhwc;
  float* vbuf = (float*)fpad;

  dim3 blk(256);
  // weight packs
  pack_w<<<dim3(1008), blk, 0, stream>>>(ffw,   ffwpack,  448, 64, 4, 258048);
  pack_w<<<dim3(144),  blk, 0, stream>>>(bw2,   c2pack,    64, 64, 4, 36864);
  pack_w<<<dim3(432),  blk, 0, stream>>>(omw,   ompack,    64, 189, 12, 110592);
  pack_w<<<dim3(144),  blk, 0, stream>>>(dn1w,  dn1pack,   64, 64, 4, 36864);
  pack_w<<<dim3(144),  blk, 0, stream>>>(dn2w,  dn2pack,   64, 64, 4, 36864);
  pack_w<<<dim3(144),  blk, 0, stream>>>(trcw,  trcpack,   64, 64, 4, 36864);
  pack_w<<<dim3(288),  blk, 0, stream>>>(up2cw, up2cpack, 128, 64, 4, 73728);
  pack_w<<<dim3(288),  blk, 0, stream>>>(up1cw, up1cpack, 128, 64, 4, 73728);
  repack_convT_w<<<dim3(64), blk, 0, stream>>>(trtw,  wp0);
  repack_convT_w<<<dim3(64), blk, 0, stream>>>(up2tw, wp1);
  repack_convT_w<<<dim3(64), blk, 0, stream>>>(up1tw, wp2);
  // pad borders (regions not yet aliased)
  padzero2<<<dim3(194,7), blk, 0, stream>>>(bbpad, 64, PDIM, PIMG64);
  padzero2<<<dim3(1352,1), blk, 0, stream>>>(fpad, 448, PDIM, 0);
  padzero2<<<dim3(194,1), blk, 0, stream>>>(out0pad, 64, PDIM, 0);
  padzero2<<<dim3(194,1), blk, 0, stream>>>(cat1pad, 128, 98, 0);
  padzero2<<<dim3(98,1),  blk, 0, stream>>>(cat2pad, 128, 50, 0);
  // backbone lqs -> fpad (NHWC448 padded; per-img channel offset via outImgStride=64)
  conv1_k<<<dim3(144,7), blk, 0, stream>>>(lqs, bw1, bb1, bbpad);
  gconv2<4,1,2,1,1,0><<<dim3(576,1,7), blk, 0, stream>>>(bbpad, nullptr, c2pack, bb2, nullptr, fpad,
      64, 192, 12, PDIM, 64, 0, PIMG64, 64, PDIM, 448, 0);
  // backbone preds -> prednhwc (NHWC64 tight)
  conv1_k<<<dim3(144,7), blk, 0, stream>>>(preds, bw1, bb1, bbpad);
  gconv2<4,1,2,1,2,0><<<dim3(576,1,7), blk, 0, stream>>>(bbpad, nullptr, c2pack, bb2, nullptr, prednhwc,
      64, 192, 12, PDIM, 64, 0, PIMG64, (size_t)HWF*64, 192, 64, 0);
  // gate (+warp) -> spad (reuses bbpad region)
  padzero2<<<dim3(1352,1), blk, 0, stream>>>(spad, 448, PDIM, 0);
  gate_nhwc<<<dim3(144,7), blk, 0, stream>>>(fpad, prednhwc, mv, spad);
  // fused dual conv -> out0pad (bf16 NHWC64 padded)
  gconv2<4,2,14,1,1,0><<<dim3(576,1,1), blk, 0, stream>>>(spad, fpad, ffwpack, ffb, nullptr, out0pad,
      64, 192, 12, PDIM, 448, 0, 0, 0, PDIM, 64, 0);
  // U-Net: downs (stride-2 MFMA), writing into concat halves
  gconv2<4,1,2,2,1,1><<<dim3(144,1,1), blk, 0, stream>>>(out0pad, nullptr, dn1pack, dn1b, nullptr, cat1pad,
      64, 96, 6, PDIM, 64, 0, 0, 0, 98, 128, 64);       // out1 -> cat1[64:]
  gconv2<4,1,2,2,1,1><<<dim3(36,1,1), blk, 0, stream>>>(cat1pad, nullptr, dn2pack, dn2b, nullptr, cat2pad,
      64, 48, 3, 98, 128, 64, 0, 0, 50, 128, 64);       // out2 -> cat2[64:]
  gconv2<4,1,2,2,0,1><<<dim3(12,1,1), blk, 0, stream>>>(cat2pad, nullptr, trcpack, trcb, t0, nullptr,
      64, 24, 2, 50, 128, 64, 0, 0, 0, 0, 0);           // t0 (fp32 NCHW)
  convT_tile2<<<dim3(4,9), blk, 0, stream>>>(t0, wp0, trtb, cat2pad, 24, 3, 50, 128, 0);   // t1 -> cat2[:64]
  gconv2<4,1,4,1,0,1><<<dim3(36,1,1), blk, 0, stream>>>(cat2pad, nullptr, up2cpack, up2cb, u2, nullptr,
      64, 48, 3, 50, 128, 0, 0, 0, 0, 0, 0);            // u2 (fp32 NCHW)
  convT_tile2<<<dim3(4,36), blk, 0, stream>>>(u2, wp1, up2tb, cat1pad, 48, 6, 98, 128, 0); // u2t -> cat1[:64]
  gconv2<4,1,4,1,0,1><<<dim3(144,1,1), blk, 0, stream>>>(cat1pad, nullptr, up1cpack, up1cb, u1, nullptr,
      64, 96, 6, 98, 128, 0, 0, 0, 0, 0, 0);            // u1 (fp32 NCHW)
  // final convT writes featfpad (reuses bbpad/spad region, dead after fuse)
  padzero2<<<dim3(194,1), blk, 0, stream>>>(featfpad, 64, PDIM, 0);
  convT_tile2<<<dim3(4,144), blk, 0, stream>>>(u1, wp2, up1tb, featfpad, 96, 12, PDIM, 64, 0);
  // offsets/masks conv (64 -> 189) -> om (fp32 NCHW, reuses prednhwc region)
  gconv2<12,1,2,1,0,0><<<dim3(576,1,1), blk, 0, stream>>>(featfpad, nullptr, ompack, omb, om, nullptr,
      189, 192, 12, PDIM, 64, 0, 0, 0, 0, 0, 0);
  // deformable conv
  deform_sample_k<<<dim3(144,7), blk, 0, stream>>>(lqs, om, vbuf);
  deform_out_k<<<dim3(144,4), blk, 0, stream>>>(vbuf, dcw, dcb, outp);
}